// Round 1
// baseline (355.429 us; speedup 1.0000x reference)
//
#include <hip/hip_runtime.h>
#include <hip/hip_bf16.h>
#include <math.h>

#define N_NODES 20000
#define N_EDGES 320000
#define N_ETOT  (N_EDGES + N_NODES)
#define SLOPE 0.2f
#define LN_EPS 1e-5f

__device__ __forceinline__ float lrelu(float x) { return x > 0.f ? x : SLOPE * x; }

// ---------------- graph build: dst-grouped CSR ----------------
__global__ __launch_bounds__(256) void k_count(const int* __restrict__ ei, int* __restrict__ cnt) {
  int i = blockIdx.x * 256 + threadIdx.x;
  if (i >= N_ETOT) return;
  int d = (i < N_EDGES) ? ei[N_EDGES + i] : (i - N_EDGES);
  atomicAdd(&cnt[d], 1);
}

__global__ __launch_bounds__(1024) void k_scan(const int* __restrict__ cnt, int* __restrict__ off) {
  __shared__ int lds[1024];
  __shared__ int base_s;
  int tid = threadIdx.x;
  if (tid == 0) { base_s = 0; off[0] = 0; }
  __syncthreads();
  for (int start = 0; start < N_NODES; start += 1024) {
    int i = start + tid;
    int v = (i < N_NODES) ? cnt[i] : 0;
    lds[tid] = v;
    __syncthreads();
    for (int s = 1; s < 1024; s <<= 1) {
      int t = (tid >= s) ? lds[tid - s] : 0;
      __syncthreads();
      lds[tid] += t;
      __syncthreads();
    }
    int incl = lds[tid];
    int base = base_s;
    if (i < N_NODES) off[i + 1] = base + incl;
    __syncthreads();
    if (tid == 1023) base_s = base + incl;
    __syncthreads();
  }
}

__global__ __launch_bounds__(256) void k_scatter(const int* __restrict__ ei, const int* __restrict__ off,
                                                 int* __restrict__ cursor, int* __restrict__ srcs) {
  int i = blockIdx.x * 256 + threadIdx.x;
  if (i >= N_ETOT) return;
  int s, d;
  if (i < N_EDGES) { s = ei[i]; d = ei[N_EDGES + i]; } else { s = i - N_EDGES; d = s; }
  int pos = off[d] + atomicAdd(&cursor[d], 1);
  srcs[pos] = s;
}

// ---------------- f32 GEMM: C[M,256] = A[M,256] @ B[256,256] ----------------
__global__ __launch_bounds__(256) void k_gemm(const float* __restrict__ A, const float* __restrict__ B,
                                              float* __restrict__ C, int M) {
  __shared__ float As[16][68];  // [k][m], padded stride 68 (16B-aligned rows, low conflict)
  __shared__ float Bs[16][68];  // [k][n]
  int t = threadIdx.x;
  int bm = blockIdx.x * 64, bn = blockIdx.y * 64;
  float acc[4][4] = {};
  int tm = (t & 15) * 4, tn = (t >> 4) * 4;
  int ar = t >> 2, akc = (t & 3) * 4;
  int bkk = t >> 4, bnc = (t & 15) * 4;
  for (int k0 = 0; k0 < 256; k0 += 16) {
    float4 av = make_float4(0.f, 0.f, 0.f, 0.f);
    if (bm + ar < M) av = *reinterpret_cast<const float4*>(&A[(size_t)(bm + ar) * 256 + k0 + akc]);
    As[akc + 0][ar] = av.x; As[akc + 1][ar] = av.y; As[akc + 2][ar] = av.z; As[akc + 3][ar] = av.w;
    float4 bv = *reinterpret_cast<const float4*>(&B[(size_t)(k0 + bkk) * 256 + bn + bnc]);
    *reinterpret_cast<float4*>(&Bs[bkk][bnc]) = bv;
    __syncthreads();
#pragma unroll
    for (int kk = 0; kk < 16; ++kk) {
      float4 a4 = *reinterpret_cast<const float4*>(&As[kk][tm]);
      float4 b4 = *reinterpret_cast<const float4*>(&Bs[kk][tn]);
      float a[4] = {a4.x, a4.y, a4.z, a4.w};
      float b[4] = {b4.x, b4.y, b4.z, b4.w};
#pragma unroll
      for (int i = 0; i < 4; ++i)
#pragma unroll
        for (int j = 0; j < 4; ++j) acc[i][j] = fmaf(a[i], b[j], acc[i][j]);
    }
    __syncthreads();
  }
#pragma unroll
  for (int i = 0; i < 4; ++i) {
    int row = bm + tm + i;
    if (row < M) {
      float4 o = make_float4(acc[i][0], acc[i][1], acc[i][2], acc[i][3]);
      *reinterpret_cast<float4*>(&C[(size_t)row * 256 + bn + tn]) = o;
    }
  }
}

// ---------------- per-node attention logits: es/ed = <h, a_src/dst> per head ----------------
template <int HEADS>
__global__ __launch_bounds__(256) void k_dots(const float* __restrict__ h, const float* __restrict__ asrc,
                                              const float* __restrict__ adst, float* __restrict__ es,
                                              float* __restrict__ ed) {
  int w = (blockIdx.x * 256 + threadIdx.x) >> 6;
  if (w >= N_NODES) return;
  int lane = threadIdx.x & 63;
  float4 hv = *reinterpret_cast<const float4*>(&h[(size_t)w * 256 + lane * 4]);
  float4 as = *reinterpret_cast<const float4*>(&asrc[lane * 4]);
  float4 ad = *reinterpret_cast<const float4*>(&adst[lane * 4]);
  float ps = hv.x * as.x + hv.y * as.y + hv.z * as.z + hv.w * as.w;
  float pd = hv.x * ad.x + hv.y * ad.y + hv.z * ad.z + hv.w * ad.w;
  const int G = 64 / HEADS;  // lanes per head (channel layout matches flat a vectors)
#pragma unroll
  for (int s = 1; s < G; s <<= 1) { ps += __shfl_xor(ps, s); pd += __shfl_xor(pd, s); }
  if ((lane & (G - 1)) == 0) {
    int hh = lane / G;
    es[(size_t)w * HEADS + hh] = ps;
    ed[(size_t)w * HEADS + hh] = pd;
  }
}

// ---------------- layer 1 aggregate (4 heads x 64ch) + bias + LayerNorm + ReLU ----------------
__global__ __launch_bounds__(256) void k_gat1_ln(const float* __restrict__ h1, const float* __restrict__ es,
                                                 const float* __restrict__ ed, const int* __restrict__ off,
                                                 const int* __restrict__ srcs, const float* __restrict__ b1,
                                                 const float* __restrict__ lng, const float* __restrict__ lnb,
                                                 float* __restrict__ hmid) {
  int n = (blockIdx.x * 256 + threadIdx.x) >> 6;
  if (n >= N_NODES) return;
  int lane = threadIdx.x & 63;
  int h = lane >> 4;  // channels 4*lane..4*lane+3 all belong to head lane/16
  int beg = off[n], end = off[n + 1];
  float e0 = ed[n * 4 + 0], e1 = ed[n * 4 + 1], e2 = ed[n * 4 + 2], e3 = ed[n * 4 + 3];
  float m0 = -1e30f, m1 = -1e30f, m2 = -1e30f, m3 = -1e30f;
  for (int j = beg + lane; j < end; j += 64) {
    int s = srcs[j];
    m0 = fmaxf(m0, lrelu(es[s * 4 + 0] + e0));
    m1 = fmaxf(m1, lrelu(es[s * 4 + 1] + e1));
    m2 = fmaxf(m2, lrelu(es[s * 4 + 2] + e2));
    m3 = fmaxf(m3, lrelu(es[s * 4 + 3] + e3));
  }
#pragma unroll
  for (int s = 1; s < 64; s <<= 1) {
    m0 = fmaxf(m0, __shfl_xor(m0, s));
    m1 = fmaxf(m1, __shfl_xor(m1, s));
    m2 = fmaxf(m2, __shfl_xor(m2, s));
    m3 = fmaxf(m3, __shfl_xor(m3, s));
  }
  float edh = (h == 0) ? e0 : (h == 1) ? e1 : (h == 2) ? e2 : e3;
  float mh  = (h == 0) ? m0 : (h == 1) ? m1 : (h == 2) ? m2 : m3;
  float den = 0.f, ax = 0.f, ay = 0.f, az = 0.f, aw = 0.f;
  for (int j = beg; j < end; ++j) {
    int s = srcs[j];
    float e = lrelu(es[s * 4 + h] + edh);
    float w = __expf(e - mh);
    den += w;
    float4 hv = *reinterpret_cast<const float4*>(&h1[(size_t)s * 256 + lane * 4]);
    ax = fmaf(w, hv.x, ax); ay = fmaf(w, hv.y, ay);
    az = fmaf(w, hv.z, az); aw = fmaf(w, hv.w, aw);
  }
  float inv = 1.f / den;
  float4 bb = *reinterpret_cast<const float4*>(&b1[lane * 4]);
  float vx = ax * inv + bb.x, vy = ay * inv + bb.y, vz = az * inv + bb.z, vw = aw * inv + bb.w;
  float sum = vx + vy + vz + vw;
  float sq = vx * vx + vy * vy + vz * vz + vw * vw;
#pragma unroll
  for (int s = 1; s < 64; s <<= 1) { sum += __shfl_xor(sum, s); sq += __shfl_xor(sq, s); }
  float mu = sum * (1.f / 256.f);
  float var = sq * (1.f / 256.f) - mu * mu;
  float rstd = rsqrtf(var + LN_EPS);
  float4 g = *reinterpret_cast<const float4*>(&lng[lane * 4]);
  float4 lb = *reinterpret_cast<const float4*>(&lnb[lane * 4]);
  float4 o;
  o.x = fmaxf(0.f, (vx - mu) * rstd * g.x + lb.x);
  o.y = fmaxf(0.f, (vy - mu) * rstd * g.y + lb.y);
  o.z = fmaxf(0.f, (vz - mu) * rstd * g.z + lb.z);
  o.w = fmaxf(0.f, (vw - mu) * rstd * g.w + lb.w);
  *reinterpret_cast<float4*>(&hmid[(size_t)n * 256 + lane * 4]) = o;
}

// ---------------- layer 2 aggregate (1 head x 256ch) + bias -> out ----------------
__global__ __launch_bounds__(256) void k_gat2(const float* __restrict__ h2, const float* __restrict__ es,
                                              const float* __restrict__ ed, const int* __restrict__ off,
                                              const int* __restrict__ srcs, const float* __restrict__ b2,
                                              float* __restrict__ out) {
  int n = (blockIdx.x * 256 + threadIdx.x) >> 6;
  if (n >= N_NODES) return;
  int lane = threadIdx.x & 63;
  int beg = off[n], end = off[n + 1];
  float edn = ed[n];
  float m = -1e30f;
  for (int j = beg + lane; j < end; j += 64) m = fmaxf(m, lrelu(es[srcs[j]] + edn));
#pragma unroll
  for (int s = 1; s < 64; s <<= 1) m = fmaxf(m, __shfl_xor(m, s));
  float den = 0.f, ax = 0.f, ay = 0.f, az = 0.f, aw = 0.f;
  for (int j = beg; j < end; ++j) {
    int s = srcs[j];
    float w = __expf(lrelu(es[s] + edn) - m);
    den += w;
    float4 hv = *reinterpret_cast<const float4*>(&h2[(size_t)s * 256 + lane * 4]);
    ax = fmaf(w, hv.x, ax); ay = fmaf(w, hv.y, ay);
    az = fmaf(w, hv.z, az); aw = fmaf(w, hv.w, aw);
  }
  float inv = 1.f / den;
  float4 bb = *reinterpret_cast<const float4*>(&b2[lane * 4]);
  float4 o = make_float4(ax * inv + bb.x, ay * inv + bb.y, az * inv + bb.z, aw * inv + bb.w);
  *reinterpret_cast<float4*>(&out[(size_t)n * 256 + lane * 4]) = o;
}

extern "C" void kernel_launch(void* const* d_in, const int* in_sizes, int n_in,
                              void* d_out, int out_size, void* d_ws, size_t ws_size,
                              hipStream_t stream) {
  (void)in_sizes; (void)n_in; (void)out_size; (void)ws_size;
  const float* x   = (const float*)d_in[0];
  const int*   ei  = (const int*)d_in[1];
  const float* W1  = (const float*)d_in[2];
  const float* a1s = (const float*)d_in[3];
  const float* a1d = (const float*)d_in[4];
  const float* b1  = (const float*)d_in[5];
  const float* lng = (const float*)d_in[6];
  const float* lnb = (const float*)d_in[7];
  const float* W2  = (const float*)d_in[8];
  const float* a2s = (const float*)d_in[9];
  const float* a2d = (const float*)d_in[10];
  const float* b2  = (const float*)d_in[11];
  float* out = (float*)d_out;

  char* ws = (char*)d_ws;
  float* h1   = (float*)(ws + 0);           // 20,480,000 B
  float* hmid = (float*)(ws + 20480000);
  float* h2   = (float*)(ws + 40960000);
  float* es1  = (float*)(ws + 61440000);    // N*4 f32
  float* ed1  = (float*)(ws + 61760000);
  float* es2  = (float*)(ws + 62080000);    // N f32
  float* ed2  = (float*)(ws + 62160000);
  int*   off  = (int*)(ws + 62240000);      // N+1
  int*   cnt  = (int*)(ws + 62320016);      // N
  int*   srcs = (int*)(ws + 62400016);      // ETOT

  // CSR build (ws re-poisoned every call -> rebuild)
  hipMemsetAsync(cnt, 0, N_NODES * sizeof(int), stream);
  k_count<<<(N_ETOT + 255) / 256, 256, 0, stream>>>(ei, cnt);
  k_scan<<<1, 1024, 0, stream>>>(cnt, off);
  hipMemsetAsync(cnt, 0, N_NODES * sizeof(int), stream);
  k_scatter<<<(N_ETOT + 255) / 256, 256, 0, stream>>>(ei, off, cnt, srcs);

  dim3 gg((N_NODES + 63) / 64, 4);
  k_gemm<<<gg, 256, 0, stream>>>(x, W1, h1, N_NODES);
  k_dots<4><<<(N_NODES * 64) / 256, 256, 0, stream>>>(h1, a1s, a1d, es1, ed1);
  k_gat1_ln<<<(N_NODES * 64) / 256, 256, 0, stream>>>(h1, es1, ed1, off, srcs, b1, lng, lnb, hmid);
  k_gemm<<<gg, 256, 0, stream>>>(hmid, W2, h2, N_NODES);
  k_dots<1><<<(N_NODES * 64) / 256, 256, 0, stream>>>(h2, a2s, a2d, es2, ed2);
  k_gat2<<<(N_NODES * 64) / 256, 256, 0, stream>>>(h2, es2, ed2, off, srcs, b2, out);
}

// Round 2
// 296.862 us; speedup vs baseline: 1.1973x; 1.1973x over previous
//
#include <hip/hip_runtime.h>
#include <hip/hip_bf16.h>
#include <math.h>

#define N_NODES 20000
#define N_EDGES 320000
#define N_ETOT  (N_EDGES + N_NODES)
#define SLOPE 0.2f
#define LN_EPS 1e-5f

__device__ __forceinline__ float lrelu(float x) { return x > 0.f ? x : SLOPE * x; }

__device__ __forceinline__ float rlf(float v, int l) {
  return __uint_as_float(__builtin_amdgcn_readlane(__float_as_uint(v), l));
}
__device__ __forceinline__ int rli(int v, int l) { return __builtin_amdgcn_readlane(v, l); }

__device__ __forceinline__ unsigned short f2bf(float f) {
  __hip_bfloat16 h = __float2bfloat16(f);
  return *reinterpret_cast<unsigned short*>(&h);
}
__device__ __forceinline__ float bf2f(unsigned short u) {
  unsigned int x = ((unsigned int)u) << 16;
  return __uint_as_float(x);
}

// ---------------- graph build: dst-grouped CSR ----------------
__global__ __launch_bounds__(256) void k_count(const int* __restrict__ ei, int* __restrict__ cnt) {
  int i = blockIdx.x * 256 + threadIdx.x;
  if (i >= N_ETOT) return;
  int d = (i < N_EDGES) ? ei[N_EDGES + i] : (i - N_EDGES);
  atomicAdd(&cnt[d], 1);
}

__global__ __launch_bounds__(1024) void k_scan(const int* __restrict__ cnt, int* __restrict__ off) {
  __shared__ int lds[1024];
  __shared__ int base_s;
  int tid = threadIdx.x;
  if (tid == 0) { base_s = 0; off[0] = 0; }
  __syncthreads();
  for (int start = 0; start < N_NODES; start += 1024) {
    int i = start + tid;
    int v = (i < N_NODES) ? cnt[i] : 0;
    lds[tid] = v;
    __syncthreads();
    for (int s = 1; s < 1024; s <<= 1) {
      int t = (tid >= s) ? lds[tid - s] : 0;
      __syncthreads();
      lds[tid] += t;
      __syncthreads();
    }
    int incl = lds[tid];
    int base = base_s;
    if (i < N_NODES) off[i + 1] = base + incl;
    __syncthreads();
    if (tid == 1023) base_s = base + incl;
    __syncthreads();
  }
}

__global__ __launch_bounds__(256) void k_scatter(const int* __restrict__ ei, const int* __restrict__ off,
                                                 int* __restrict__ cursor, int* __restrict__ srcs) {
  int i = blockIdx.x * 256 + threadIdx.x;
  if (i >= N_ETOT) return;
  int s, d;
  if (i < N_EDGES) { s = ei[i]; d = ei[N_EDGES + i]; } else { s = i - N_EDGES; d = s; }
  int pos = off[d] + atomicAdd(&cursor[d], 1);
  srcs[pos] = s;
}

// ---------------- f32 GEMM: C[M,256] = A[M,256] @ B[256,256]; epilogue f32 or bf16 ----------------
template <int OUTBF>
__global__ __launch_bounds__(256) void k_gemm(const float* __restrict__ A, const float* __restrict__ B,
                                              void* __restrict__ Cv, int M) {
  __shared__ float As[16][68];
  __shared__ float Bs[16][68];
  int t = threadIdx.x;
  int bm = blockIdx.x * 64, bn = blockIdx.y * 64;
  float acc[4][4] = {};
  int tm = (t & 15) * 4, tn = (t >> 4) * 4;
  int ar = t >> 2, akc = (t & 3) * 4;
  int bkk = t >> 4, bnc = (t & 15) * 4;
  for (int k0 = 0; k0 < 256; k0 += 16) {
    float4 av = make_float4(0.f, 0.f, 0.f, 0.f);
    if (bm + ar < M) av = *reinterpret_cast<const float4*>(&A[(size_t)(bm + ar) * 256 + k0 + akc]);
    As[akc + 0][ar] = av.x; As[akc + 1][ar] = av.y; As[akc + 2][ar] = av.z; As[akc + 3][ar] = av.w;
    float4 bv = *reinterpret_cast<const float4*>(&B[(size_t)(k0 + bkk) * 256 + bn + bnc]);
    *reinterpret_cast<float4*>(&Bs[bkk][bnc]) = bv;
    __syncthreads();
#pragma unroll
    for (int kk = 0; kk < 16; ++kk) {
      float4 a4 = *reinterpret_cast<const float4*>(&As[kk][tm]);
      float4 b4 = *reinterpret_cast<const float4*>(&Bs[kk][tn]);
      float a[4] = {a4.x, a4.y, a4.z, a4.w};
      float b[4] = {b4.x, b4.y, b4.z, b4.w};
#pragma unroll
      for (int i = 0; i < 4; ++i)
#pragma unroll
        for (int j = 0; j < 4; ++j) acc[i][j] = fmaf(a[i], b[j], acc[i][j]);
    }
    __syncthreads();
  }
#pragma unroll
  for (int i = 0; i < 4; ++i) {
    int row = bm + tm + i;
    if (row < M) {
      if (OUTBF) {
        ushort4 o;
        o.x = f2bf(acc[i][0]); o.y = f2bf(acc[i][1]); o.z = f2bf(acc[i][2]); o.w = f2bf(acc[i][3]);
        *reinterpret_cast<ushort4*>(&((unsigned short*)Cv)[(size_t)row * 256 + bn + tn]) = o;
      } else {
        float4 o = make_float4(acc[i][0], acc[i][1], acc[i][2], acc[i][3]);
        *reinterpret_cast<float4*>(&((float*)Cv)[(size_t)row * 256 + bn + tn]) = o;
      }
    }
  }
}

// ---------------- per-node attention logits from bf16 h ----------------
template <int HEADS>
__global__ __launch_bounds__(256) void k_dots(const unsigned short* __restrict__ h, const float* __restrict__ asrc,
                                              const float* __restrict__ adst, float* __restrict__ es,
                                              float* __restrict__ ed) {
  int w = (blockIdx.x * 256 + threadIdx.x) >> 6;
  if (w >= N_NODES) return;
  int lane = threadIdx.x & 63;
  ushort4 hv4 = *reinterpret_cast<const ushort4*>(&h[(size_t)w * 256 + lane * 4]);
  float hx = bf2f(hv4.x), hy = bf2f(hv4.y), hz = bf2f(hv4.z), hw = bf2f(hv4.w);
  float4 as = *reinterpret_cast<const float4*>(&asrc[lane * 4]);
  float4 ad = *reinterpret_cast<const float4*>(&adst[lane * 4]);
  float ps = hx * as.x + hy * as.y + hz * as.z + hw * as.w;
  float pd = hx * ad.x + hy * ad.y + hz * ad.z + hw * ad.w;
  const int G = 64 / HEADS;
#pragma unroll
  for (int s = 1; s < G; s <<= 1) { ps += __shfl_xor(ps, s); pd += __shfl_xor(pd, s); }
  if ((lane & (G - 1)) == 0) {
    int hh = lane / G;
    es[(size_t)w * HEADS + hh] = ps;
    ed[(size_t)w * HEADS + hh] = pd;
  }
}

// ---------------- layer 1 aggregate (4 heads x 64ch, bf16 h) + bias + LN + ReLU ----------------
__global__ __launch_bounds__(256) void k_gat1_ln(const unsigned short* __restrict__ h1,
                                                 const float* __restrict__ es, const float* __restrict__ ed,
                                                 const int* __restrict__ off, const int* __restrict__ srcs,
                                                 const float* __restrict__ b1, const float* __restrict__ lng,
                                                 const float* __restrict__ lnb, float* __restrict__ hmid) {
  int n = (blockIdx.x * 256 + threadIdx.x) >> 6;
  if (n >= N_NODES) return;
  int lane = threadIdx.x & 63;
  int myh = lane >> 4;
  int beg = off[n], end = off[n + 1], deg = end - beg;
  float4 edv = *reinterpret_cast<const float4*>(&ed[n * 4]);
  float ax = 0.f, ay = 0.f, az = 0.f, aw = 0.f;
  float invden;

  if (deg <= 64) {
    // ---- fast path: all edge metadata register-resident ----
    int sv = 0;
    float e0 = -1e30f, e1 = -1e30f, e2 = -1e30f, e3 = -1e30f;
    bool valid = lane < deg;
    if (valid) {
      sv = srcs[beg + lane];
      float4 esv = *reinterpret_cast<const float4*>(&es[sv * 4]);
      e0 = lrelu(esv.x + edv.x); e1 = lrelu(esv.y + edv.y);
      e2 = lrelu(esv.z + edv.z); e3 = lrelu(esv.w + edv.w);
    }
    float m0 = e0, m1 = e1, m2 = e2, m3 = e3;
#pragma unroll
    for (int s = 1; s < 64; s <<= 1) {
      m0 = fmaxf(m0, __shfl_xor(m0, s)); m1 = fmaxf(m1, __shfl_xor(m1, s));
      m2 = fmaxf(m2, __shfl_xor(m2, s)); m3 = fmaxf(m3, __shfl_xor(m3, s));
    }
    float w0 = valid ? __expf(e0 - m0) : 0.f;
    float w1 = valid ? __expf(e1 - m1) : 0.f;
    float w2 = valid ? __expf(e2 - m2) : 0.f;
    float w3 = valid ? __expf(e3 - m3) : 0.f;
    float d0 = w0, d1 = w1, d2 = w2, d3 = w3;
#pragma unroll
    for (int s = 1; s < 64; s <<= 1) {
      d0 += __shfl_xor(d0, s); d1 += __shfl_xor(d1, s);
      d2 += __shfl_xor(d2, s); d3 += __shfl_xor(d3, s);
    }
    float den = (myh == 0) ? d0 : (myh == 1) ? d1 : (myh == 2) ? d2 : d3;
    invden = 1.f / den;

    int j = 0;
    for (; j + 4 <= deg; j += 4) {
      int s0 = rli(sv, j), s1 = rli(sv, j + 1), s2 = rli(sv, j + 2), s3 = rli(sv, j + 3);
      ushort4 v0 = *reinterpret_cast<const ushort4*>(&h1[(size_t)s0 * 256 + lane * 4]);
      ushort4 v1 = *reinterpret_cast<const ushort4*>(&h1[(size_t)s1 * 256 + lane * 4]);
      ushort4 v2 = *reinterpret_cast<const ushort4*>(&h1[(size_t)s2 * 256 + lane * 4]);
      ushort4 v3 = *reinterpret_cast<const ushort4*>(&h1[(size_t)s3 * 256 + lane * 4]);
#pragma unroll
      for (int q = 0; q < 4; ++q) {
        int jj = j + q;
        float w0j = rlf(w0, jj), w1j = rlf(w1, jj), w2j = rlf(w2, jj), w3j = rlf(w3, jj);
        float wj = (myh == 0) ? w0j : (myh == 1) ? w1j : (myh == 2) ? w2j : w3j;
        ushort4 v = (q == 0) ? v0 : (q == 1) ? v1 : (q == 2) ? v2 : v3;
        ax = fmaf(wj, bf2f(v.x), ax); ay = fmaf(wj, bf2f(v.y), ay);
        az = fmaf(wj, bf2f(v.z), az); aw = fmaf(wj, bf2f(v.w), aw);
      }
    }
    for (; j < deg; ++j) {
      int sj = rli(sv, j);
      float w0j = rlf(w0, j), w1j = rlf(w1, j), w2j = rlf(w2, j), w3j = rlf(w3, j);
      float wj = (myh == 0) ? w0j : (myh == 1) ? w1j : (myh == 2) ? w2j : w3j;
      ushort4 v = *reinterpret_cast<const ushort4*>(&h1[(size_t)sj * 256 + lane * 4]);
      ax = fmaf(wj, bf2f(v.x), ax); ay = fmaf(wj, bf2f(v.y), ay);
      az = fmaf(wj, bf2f(v.z), az); aw = fmaf(wj, bf2f(v.w), aw);
    }
  } else {
    // ---- generic fallback (deg > 64; ~never taken) ----
    float m0 = -1e30f, m1 = -1e30f, m2 = -1e30f, m3 = -1e30f;
    for (int j = beg + lane; j < end; j += 64) {
      int s = srcs[j];
      float4 esv = *reinterpret_cast<const float4*>(&es[s * 4]);
      m0 = fmaxf(m0, lrelu(esv.x + edv.x)); m1 = fmaxf(m1, lrelu(esv.y + edv.y));
      m2 = fmaxf(m2, lrelu(esv.z + edv.z)); m3 = fmaxf(m3, lrelu(esv.w + edv.w));
    }
#pragma unroll
    for (int s = 1; s < 64; s <<= 1) {
      m0 = fmaxf(m0, __shfl_xor(m0, s)); m1 = fmaxf(m1, __shfl_xor(m1, s));
      m2 = fmaxf(m2, __shfl_xor(m2, s)); m3 = fmaxf(m3, __shfl_xor(m3, s));
    }
    float edh = (myh == 0) ? edv.x : (myh == 1) ? edv.y : (myh == 2) ? edv.z : edv.w;
    float mh = (myh == 0) ? m0 : (myh == 1) ? m1 : (myh == 2) ? m2 : m3;
    float den = 0.f;
    for (int j = beg; j < end; ++j) {
      int s = srcs[j];
      float e = lrelu(es[s * 4 + myh] + edh);
      float w = __expf(e - mh);
      den += w;
      ushort4 v = *reinterpret_cast<const ushort4*>(&h1[(size_t)s * 256 + lane * 4]);
      ax = fmaf(w, bf2f(v.x), ax); ay = fmaf(w, bf2f(v.y), ay);
      az = fmaf(w, bf2f(v.z), az); aw = fmaf(w, bf2f(v.w), aw);
    }
    invden = 1.f / den;
  }

  float4 bb = *reinterpret_cast<const float4*>(&b1[lane * 4]);
  float vx = ax * invden + bb.x, vy = ay * invden + bb.y;
  float vz = az * invden + bb.z, vw = aw * invden + bb.w;
  float sum = vx + vy + vz + vw;
  float sq = vx * vx + vy * vy + vz * vz + vw * vw;
#pragma unroll
  for (int s = 1; s < 64; s <<= 1) { sum += __shfl_xor(sum, s); sq += __shfl_xor(sq, s); }
  float mu = sum * (1.f / 256.f);
  float var = sq * (1.f / 256.f) - mu * mu;
  float rstd = rsqrtf(var + LN_EPS);
  float4 g = *reinterpret_cast<const float4*>(&lng[lane * 4]);
  float4 lb = *reinterpret_cast<const float4*>(&lnb[lane * 4]);
  float4 o;
  o.x = fmaxf(0.f, (vx - mu) * rstd * g.x + lb.x);
  o.y = fmaxf(0.f, (vy - mu) * rstd * g.y + lb.y);
  o.z = fmaxf(0.f, (vz - mu) * rstd * g.z + lb.z);
  o.w = fmaxf(0.f, (vw - mu) * rstd * g.w + lb.w);
  *reinterpret_cast<float4*>(&hmid[(size_t)n * 256 + lane * 4]) = o;
}

// ---------------- layer 2 aggregate (1 head x 256ch, bf16 h) + bias -> out ----------------
__global__ __launch_bounds__(256) void k_gat2(const unsigned short* __restrict__ h2,
                                              const float* __restrict__ es, const float* __restrict__ ed,
                                              const int* __restrict__ off, const int* __restrict__ srcs,
                                              const float* __restrict__ b2, float* __restrict__ out) {
  int n = (blockIdx.x * 256 + threadIdx.x) >> 6;
  if (n >= N_NODES) return;
  int lane = threadIdx.x & 63;
  int beg = off[n], end = off[n + 1], deg = end - beg;
  float edn = ed[n];
  float ax = 0.f, ay = 0.f, az = 0.f, aw = 0.f;
  float invden;

  if (deg <= 64) {
    int sv = 0;
    float e = -1e30f;
    bool valid = lane < deg;
    if (valid) {
      sv = srcs[beg + lane];
      e = lrelu(es[sv] + edn);
    }
    float m = e;
#pragma unroll
    for (int s = 1; s < 64; s <<= 1) m = fmaxf(m, __shfl_xor(m, s));
    float wv = valid ? __expf(e - m) : 0.f;
    float den = wv;
#pragma unroll
    for (int s = 1; s < 64; s <<= 1) den += __shfl_xor(den, s);
    invden = 1.f / den;

    int j = 0;
    for (; j + 4 <= deg; j += 4) {
      int s0 = rli(sv, j), s1 = rli(sv, j + 1), s2 = rli(sv, j + 2), s3 = rli(sv, j + 3);
      ushort4 v0 = *reinterpret_cast<const ushort4*>(&h2[(size_t)s0 * 256 + lane * 4]);
      ushort4 v1 = *reinterpret_cast<const ushort4*>(&h2[(size_t)s1 * 256 + lane * 4]);
      ushort4 v2 = *reinterpret_cast<const ushort4*>(&h2[(size_t)s2 * 256 + lane * 4]);
      ushort4 v3 = *reinterpret_cast<const ushort4*>(&h2[(size_t)s3 * 256 + lane * 4]);
      float wj0 = rlf(wv, j), wj1 = rlf(wv, j + 1), wj2 = rlf(wv, j + 2), wj3 = rlf(wv, j + 3);
      ax = fmaf(wj0, bf2f(v0.x), ax); ay = fmaf(wj0, bf2f(v0.y), ay);
      az = fmaf(wj0, bf2f(v0.z), az); aw = fmaf(wj0, bf2f(v0.w), aw);
      ax = fmaf(wj1, bf2f(v1.x), ax); ay = fmaf(wj1, bf2f(v1.y), ay);
      az = fmaf(wj1, bf2f(v1.z), az); aw = fmaf(wj1, bf2f(v1.w), aw);
      ax = fmaf(wj2, bf2f(v2.x), ax); ay = fmaf(wj2, bf2f(v2.y), ay);
      az = fmaf(wj2, bf2f(v2.z), az); aw = fmaf(wj2, bf2f(v2.w), aw);
      ax = fmaf(wj3, bf2f(v3.x), ax); ay = fmaf(wj3, bf2f(v3.y), ay);
      az = fmaf(wj3, bf2f(v3.z), az); aw = fmaf(wj3, bf2f(v3.w), aw);
    }
    for (; j < deg; ++j) {
      int sj = rli(sv, j);
      float wj = rlf(wv, j);
      ushort4 v = *reinterpret_cast<const ushort4*>(&h2[(size_t)sj * 256 + lane * 4]);
      ax = fmaf(wj, bf2f(v.x), ax); ay = fmaf(wj, bf2f(v.y), ay);
      az = fmaf(wj, bf2f(v.z), az); aw = fmaf(wj, bf2f(v.w), aw);
    }
  } else {
    float m = -1e30f;
    for (int j = beg + lane; j < end; j += 64) m = fmaxf(m, lrelu(es[srcs[j]] + edn));
#pragma unroll
    for (int s = 1; s < 64; s <<= 1) m = fmaxf(m, __shfl_xor(m, s));
    float den = 0.f;
    for (int j = beg; j < end; ++j) {
      int s = srcs[j];
      float w = __expf(lrelu(es[s] + edn) - m);
      den += w;
      ushort4 v = *reinterpret_cast<const ushort4*>(&h2[(size_t)s * 256 + lane * 4]);
      ax = fmaf(w, bf2f(v.x), ax); ay = fmaf(w, bf2f(v.y), ay);
      az = fmaf(w, bf2f(v.z), az); aw = fmaf(w, bf2f(v.w), aw);
    }
    invden = 1.f / den;
  }

  float4 bb = *reinterpret_cast<const float4*>(&b2[lane * 4]);
  float4 o = make_float4(ax * invden + bb.x, ay * invden + bb.y, az * invden + bb.z, aw * invden + bb.w);
  *reinterpret_cast<float4*>(&out[(size_t)n * 256 + lane * 4]) = o;
}

extern "C" void kernel_launch(void* const* d_in, const int* in_sizes, int n_in,
                              void* d_out, int out_size, void* d_ws, size_t ws_size,
                              hipStream_t stream) {
  (void)in_sizes; (void)n_in; (void)out_size; (void)ws_size;
  const float* x   = (const float*)d_in[0];
  const int*   ei  = (const int*)d_in[1];
  const float* W1  = (const float*)d_in[2];
  const float* a1s = (const float*)d_in[3];
  const float* a1d = (const float*)d_in[4];
  const float* b1  = (const float*)d_in[5];
  const float* lng = (const float*)d_in[6];
  const float* lnb = (const float*)d_in[7];
  const float* W2  = (const float*)d_in[8];
  const float* a2s = (const float*)d_in[9];
  const float* a2d = (const float*)d_in[10];
  const float* b2  = (const float*)d_in[11];
  float* out = (float*)d_out;

  char* ws = (char*)d_ws;
  float*          hmid = (float*)(ws + 0);            // 20,480,000 B
  unsigned short* h1b  = (unsigned short*)(ws + 20480000);  // 10,240,000 B
  unsigned short* h2b  = (unsigned short*)(ws + 30720000);  // 10,240,000 B
  float* es1 = (float*)(ws + 40960000);               // N*4
  float* ed1 = (float*)(ws + 41280000);
  float* es2 = (float*)(ws + 41600000);               // N
  float* ed2 = (float*)(ws + 41680000);
  int*   off = (int*)(ws + 41760000);                 // N+1
  int*   cnt = (int*)(ws + 41840016);                 // N
  int*   srcs = (int*)(ws + 41920016);                // ETOT

  hipMemsetAsync(cnt, 0, N_NODES * sizeof(int), stream);
  k_count<<<(N_ETOT + 255) / 256, 256, 0, stream>>>(ei, cnt);
  k_scan<<<1, 1024, 0, stream>>>(cnt, off);
  hipMemsetAsync(cnt, 0, N_NODES * sizeof(int), stream);
  k_scatter<<<(N_ETOT + 255) / 256, 256, 0, stream>>>(ei, off, cnt, srcs);

  dim3 gg((N_NODES + 63) / 64, 4);
  k_gemm<1><<<gg, 256, 0, stream>>>(x, W1, (void*)h1b, N_NODES);
  k_dots<4><<<(N_NODES * 64) / 256, 256, 0, stream>>>(h1b, a1s, a1d, es1, ed1);
  k_gat1_ln<<<(N_NODES * 64) / 256, 256, 0, stream>>>(h1b, es1, ed1, off, srcs, b1, lng, lnb, hmid);
  k_gemm<1><<<gg, 256, 0, stream>>>(hmid, W2, (void*)h2b, N_NODES);
  k_dots<1><<<(N_NODES * 64) / 256, 256, 0, stream>>>(h2b, a2s, a2d, es2, ed2);
  k_gat2<<<(N_NODES * 64) / 256, 256, 0, stream>>>(h2b, es2, ed2, off, srcs, b2, out);
}

// Round 3
// 273.469 us; speedup vs baseline: 1.2997x; 1.0855x over previous
//
#include <hip/hip_runtime.h>
#include <hip/hip_bf16.h>
#include <math.h>

#define N_NODES 20000
#define N_EDGES 320000
#define N_ETOT  (N_EDGES + N_NODES)
#define SLOPE 0.2f
#define LN_EPS 1e-5f

typedef __attribute__((ext_vector_type(8))) short short8v;
typedef __attribute__((ext_vector_type(4))) float f32x4;

__device__ __forceinline__ float lrelu(float x) { return x > 0.f ? x : SLOPE * x; }

__device__ __forceinline__ float rlf(float v, int l) {
  return __uint_as_float(__builtin_amdgcn_readlane(__float_as_uint(v), l));
}
__device__ __forceinline__ int rli(int v, int l) { return __builtin_amdgcn_readlane(v, l); }

__device__ __forceinline__ unsigned short f2bf(float f) {
  __hip_bfloat16 h = __float2bfloat16(f);
  return *reinterpret_cast<unsigned short*>(&h);
}
__device__ __forceinline__ float bf2f(unsigned short u) {
  return __uint_as_float(((unsigned int)u) << 16);
}

// ---------------- graph build: dst-grouped CSR ----------------
__global__ __launch_bounds__(256) void k_count(const int* __restrict__ ei, int* __restrict__ cnt) {
  int i = blockIdx.x * 256 + threadIdx.x;
  if (i >= N_ETOT) return;
  int d = (i < N_EDGES) ? ei[N_EDGES + i] : (i - N_EDGES);
  atomicAdd(&cnt[d], 1);
}

__global__ __launch_bounds__(1024) void k_scan(const int* __restrict__ cnt, int* __restrict__ off) {
  __shared__ int wsum[16], wpref[16];
  __shared__ int base_s;
  int tid = threadIdx.x, lane = tid & 63, wid = tid >> 6;
  if (tid == 0) { base_s = 0; off[0] = 0; }
  __syncthreads();
  for (int c = 0; c < 20; ++c) {
    int i = c * 1024 + tid;
    int v = (i < N_NODES) ? cnt[i] : 0;
    int incl = v;
#pragma unroll
    for (int d = 1; d < 64; d <<= 1) { int t = __shfl_up(incl, d); if (lane >= d) incl += t; }
    if (lane == 63) wsum[wid] = incl;
    __syncthreads();
    if (wid == 0 && lane < 16) {
      int s = wsum[lane];
#pragma unroll
      for (int d = 1; d < 16; d <<= 1) { int t = __shfl_up(s, d); if (lane >= d) s += t; }
      wpref[lane] = s;
    }
    __syncthreads();
    int wbase = wid ? wpref[wid - 1] : 0;
    if (i < N_NODES) off[i + 1] = base_s + wbase + incl;
    __syncthreads();
    if (tid == 0) base_s += wpref[15];
    __syncthreads();
  }
}

__global__ __launch_bounds__(256) void k_scatter(const int* __restrict__ ei, const int* __restrict__ off,
                                                 int* __restrict__ cursor, int* __restrict__ srcs) {
  int i = blockIdx.x * 256 + threadIdx.x;
  if (i >= N_ETOT) return;
  int s, d;
  if (i < N_EDGES) { s = ei[i]; d = ei[N_EDGES + i]; } else { s = i - N_EDGES; d = s; }
  int pos = off[d] + atomicAdd(&cursor[d], 1);
  srcs[pos] = s;
}

// ---------------- prep: W[256][256] f32 -> Wt[n][k] bf16 (transposed) ----------------
__global__ __launch_bounds__(256) void k_prep(const float* __restrict__ W1, const float* __restrict__ W2,
                                              unsigned short* __restrict__ W1t, unsigned short* __restrict__ W2t) {
  int b = blockIdx.x, t = threadIdx.x;
  if (b < 256) W1t[b * 256 + t] = f2bf(W1[t * 256 + b]);
  else { int n = b - 256; W2t[n * 256 + t] = f2bf(W2[t * 256 + n]); }
}

// ---------------- MFMA GEMM: C_bf16[M,256] = A[M,256] @ Wt^T ; per-wave 16x128 tile ----------------
template <int A_BF16>
__global__ __launch_bounds__(256) void k_mfma_gemm(const void* __restrict__ Av,
                                                   const unsigned short* __restrict__ Wt,
                                                   unsigned short* __restrict__ C) {
  int gwave = blockIdx.x * 4 + (threadIdx.x >> 6);
  int wtile = gwave >> 1;          // 16-row tile index, 0..1249
  int nhalf = gwave & 1;           // which 128-col half
  int lane = threadIdx.x & 63;
  int r = lane & 15, kg = lane >> 4;
  int rbase = wtile * 16;
  int cbase = nhalf * 128;

  f32x4 acc[8];
#pragma unroll
  for (int i = 0; i < 8; ++i) acc[i] = (f32x4){0.f, 0.f, 0.f, 0.f};

  const float* Af = (const float*)Av;
  const unsigned short* Ab = (const unsigned short*)Av;

#pragma unroll
  for (int ks = 0; ks < 8; ++ks) {
    int koff = ks * 32 + kg * 8;
    short8v a;
    if (A_BF16) {
      int4 raw = *reinterpret_cast<const int4*>(&Ab[(size_t)(rbase + r) * 256 + koff]);
      a = __builtin_bit_cast(short8v, raw);
    } else {
      float4 lo = *reinterpret_cast<const float4*>(&Af[(size_t)(rbase + r) * 256 + koff]);
      float4 hi = *reinterpret_cast<const float4*>(&Af[(size_t)(rbase + r) * 256 + koff + 4]);
      a[0] = (short)f2bf(lo.x); a[1] = (short)f2bf(lo.y); a[2] = (short)f2bf(lo.z); a[3] = (short)f2bf(lo.w);
      a[4] = (short)f2bf(hi.x); a[5] = (short)f2bf(hi.y); a[6] = (short)f2bf(hi.z); a[7] = (short)f2bf(hi.w);
    }
#pragma unroll
    for (int nf = 0; nf < 8; ++nf) {
      int4 braw = *reinterpret_cast<const int4*>(&Wt[(size_t)(cbase + nf * 16 + r) * 256 + koff]);
      short8v b = __builtin_bit_cast(short8v, braw);
      acc[nf] = __builtin_amdgcn_mfma_f32_16x16x32_bf16(a, b, acc[nf], 0, 0, 0);
    }
  }

#pragma unroll
  for (int nf = 0; nf < 8; ++nf) {
#pragma unroll
    for (int q = 0; q < 4; ++q) {
      int row = rbase + kg * 4 + q;
      int col = cbase + nf * 16 + r;
      C[(size_t)row * 256 + col] = f2bf(acc[nf][q]);
    }
  }
}

// ---------------- per-node attention logits from bf16 h ----------------
template <int HEADS>
__global__ __launch_bounds__(256) void k_dots(const unsigned short* __restrict__ h, const float* __restrict__ asrc,
                                              const float* __restrict__ adst, float* __restrict__ es,
                                              float* __restrict__ ed) {
  int w = (blockIdx.x * 256 + threadIdx.x) >> 6;
  if (w >= N_NODES) return;
  int lane = threadIdx.x & 63;
  ushort4 hv4 = *reinterpret_cast<const ushort4*>(&h[(size_t)w * 256 + lane * 4]);
  float hx = bf2f(hv4.x), hy = bf2f(hv4.y), hz = bf2f(hv4.z), hw = bf2f(hv4.w);
  float4 as = *reinterpret_cast<const float4*>(&asrc[lane * 4]);
  float4 ad = *reinterpret_cast<const float4*>(&adst[lane * 4]);
  float ps = hx * as.x + hy * as.y + hz * as.z + hw * as.w;
  float pd = hx * ad.x + hy * ad.y + hz * ad.z + hw * ad.w;
  const int G = 64 / HEADS;
#pragma unroll
  for (int s = 1; s < G; s <<= 1) { ps += __shfl_xor(ps, s); pd += __shfl_xor(pd, s); }
  if ((lane & (G - 1)) == 0) {
    int hh = lane / G;
    es[(size_t)w * HEADS + hh] = ps;
    ed[(size_t)w * HEADS + hh] = pd;
  }
}

// ---------------- layer 1 aggregate (4 heads x 64ch, bf16 h) + bias + LN + ReLU -> bf16 ----------------
__global__ __launch_bounds__(256) void k_gat1_ln(const unsigned short* __restrict__ h1,
                                                 const float* __restrict__ es, const float* __restrict__ ed,
                                                 const int* __restrict__ off, const int* __restrict__ srcs,
                                                 const float* __restrict__ b1, const float* __restrict__ lng,
                                                 const float* __restrict__ lnb, unsigned short* __restrict__ hmid) {
  int n = (blockIdx.x * 256 + threadIdx.x) >> 6;
  if (n >= N_NODES) return;
  int lane = threadIdx.x & 63;
  int myh = lane >> 4;
  int beg = off[n], end = off[n + 1], deg = end - beg;
  float4 edv = *reinterpret_cast<const float4*>(&ed[n * 4]);
  float ax = 0.f, ay = 0.f, az = 0.f, aw = 0.f;
  float invden;

  if (deg <= 64) {
    int sv = 0;
    float e0 = -1e30f, e1 = -1e30f, e2 = -1e30f, e3 = -1e30f;
    bool valid = lane < deg;
    if (valid) {
      sv = srcs[beg + lane];
      float4 esv = *reinterpret_cast<const float4*>(&es[sv * 4]);
      e0 = lrelu(esv.x + edv.x); e1 = lrelu(esv.y + edv.y);
      e2 = lrelu(esv.z + edv.z); e3 = lrelu(esv.w + edv.w);
    }
    float m0 = e0, m1 = e1, m2 = e2, m3 = e3;
#pragma unroll
    for (int s = 1; s < 64; s <<= 1) {
      m0 = fmaxf(m0, __shfl_xor(m0, s)); m1 = fmaxf(m1, __shfl_xor(m1, s));
      m2 = fmaxf(m2, __shfl_xor(m2, s)); m3 = fmaxf(m3, __shfl_xor(m3, s));
    }
    float w0 = valid ? __expf(e0 - m0) : 0.f;
    float w1 = valid ? __expf(e1 - m1) : 0.f;
    float w2 = valid ? __expf(e2 - m2) : 0.f;
    float w3 = valid ? __expf(e3 - m3) : 0.f;
    float d0 = w0, d1 = w1, d2 = w2, d3 = w3;
#pragma unroll
    for (int s = 1; s < 64; s <<= 1) {
      d0 += __shfl_xor(d0, s); d1 += __shfl_xor(d1, s);
      d2 += __shfl_xor(d2, s); d3 += __shfl_xor(d3, s);
    }
    float den = (myh == 0) ? d0 : (myh == 1) ? d1 : (myh == 2) ? d2 : d3;
    invden = 1.f / den;

    int j = 0;
    for (; j + 4 <= deg; j += 4) {
      int s0 = rli(sv, j), s1 = rli(sv, j + 1), s2 = rli(sv, j + 2), s3 = rli(sv, j + 3);
      ushort4 v0 = *reinterpret_cast<const ushort4*>(&h1[(size_t)s0 * 256 + lane * 4]);
      ushort4 v1 = *reinterpret_cast<const ushort4*>(&h1[(size_t)s1 * 256 + lane * 4]);
      ushort4 v2 = *reinterpret_cast<const ushort4*>(&h1[(size_t)s2 * 256 + lane * 4]);
      ushort4 v3 = *reinterpret_cast<const ushort4*>(&h1[(size_t)s3 * 256 + lane * 4]);
#pragma unroll
      for (int q = 0; q < 4; ++q) {
        int jj = j + q;
        float w0j = rlf(w0, jj), w1j = rlf(w1, jj), w2j = rlf(w2, jj), w3j = rlf(w3, jj);
        float wj = (myh == 0) ? w0j : (myh == 1) ? w1j : (myh == 2) ? w2j : w3j;
        ushort4 v = (q == 0) ? v0 : (q == 1) ? v1 : (q == 2) ? v2 : v3;
        ax = fmaf(wj, bf2f(v.x), ax); ay = fmaf(wj, bf2f(v.y), ay);
        az = fmaf(wj, bf2f(v.z), az); aw = fmaf(wj, bf2f(v.w), aw);
      }
    }
    for (; j < deg; ++j) {
      int sj = rli(sv, j);
      float w0j = rlf(w0, j), w1j = rlf(w1, j), w2j = rlf(w2, j), w3j = rlf(w3, j);
      float wj = (myh == 0) ? w0j : (myh == 1) ? w1j : (myh == 2) ? w2j : w3j;
      ushort4 v = *reinterpret_cast<const ushort4*>(&h1[(size_t)sj * 256 + lane * 4]);
      ax = fmaf(wj, bf2f(v.x), ax); ay = fmaf(wj, bf2f(v.y), ay);
      az = fmaf(wj, bf2f(v.z), az); aw = fmaf(wj, bf2f(v.w), aw);
    }
  } else {
    float m0 = -1e30f, m1 = -1e30f, m2 = -1e30f, m3 = -1e30f;
    for (int j = beg + lane; j < end; j += 64) {
      int s = srcs[j];
      float4 esv = *reinterpret_cast<const float4*>(&es[s * 4]);
      m0 = fmaxf(m0, lrelu(esv.x + edv.x)); m1 = fmaxf(m1, lrelu(esv.y + edv.y));
      m2 = fmaxf(m2, lrelu(esv.z + edv.z)); m3 = fmaxf(m3, lrelu(esv.w + edv.w));
    }
#pragma unroll
    for (int s = 1; s < 64; s <<= 1) {
      m0 = fmaxf(m0, __shfl_xor(m0, s)); m1 = fmaxf(m1, __shfl_xor(m1, s));
      m2 = fmaxf(m2, __shfl_xor(m2, s)); m3 = fmaxf(m3, __shfl_xor(m3, s));
    }
    float edh = (myh == 0) ? edv.x : (myh == 1) ? edv.y : (myh == 2) ? edv.z : edv.w;
    float mh = (myh == 0) ? m0 : (myh == 1) ? m1 : (myh == 2) ? m2 : m3;
    float den = 0.f;
    for (int j = beg; j < end; ++j) {
      int s = srcs[j];
      float e = lrelu(es[s * 4 + myh] + edh);
      float w = __expf(e - mh);
      den += w;
      ushort4 v = *reinterpret_cast<const ushort4*>(&h1[(size_t)s * 256 + lane * 4]);
      ax = fmaf(w, bf2f(v.x), ax); ay = fmaf(w, bf2f(v.y), ay);
      az = fmaf(w, bf2f(v.z), az); aw = fmaf(w, bf2f(v.w), aw);
    }
    invden = 1.f / den;
  }

  float4 bb = *reinterpret_cast<const float4*>(&b1[lane * 4]);
  float vx = ax * invden + bb.x, vy = ay * invden + bb.y;
  float vz = az * invden + bb.z, vw = aw * invden + bb.w;
  float sum = vx + vy + vz + vw;
  float sq = vx * vx + vy * vy + vz * vz + vw * vw;
#pragma unroll
  for (int s = 1; s < 64; s <<= 1) { sum += __shfl_xor(sum, s); sq += __shfl_xor(sq, s); }
  float mu = sum * (1.f / 256.f);
  float var = sq * (1.f / 256.f) - mu * mu;
  float rstd = rsqrtf(var + LN_EPS);
  float4 g = *reinterpret_cast<const float4*>(&lng[lane * 4]);
  float4 lb = *reinterpret_cast<const float4*>(&lnb[lane * 4]);
  ushort4 o;
  o.x = f2bf(fmaxf(0.f, (vx - mu) * rstd * g.x + lb.x));
  o.y = f2bf(fmaxf(0.f, (vy - mu) * rstd * g.y + lb.y));
  o.z = f2bf(fmaxf(0.f, (vz - mu) * rstd * g.z + lb.z));
  o.w = f2bf(fmaxf(0.f, (vw - mu) * rstd * g.w + lb.w));
  *reinterpret_cast<ushort4*>(&hmid[(size_t)n * 256 + lane * 4]) = o;
}

// ---------------- layer 2 aggregate (1 head x 256ch, bf16 h) + bias -> out f32 ----------------
__global__ __launch_bounds__(256) void k_gat2(const unsigned short* __restrict__ h2,
                                              const float* __restrict__ es, const float* __restrict__ ed,
                                              const int* __restrict__ off, const int* __restrict__ srcs,
                                              const float* __restrict__ b2, float* __restrict__ out) {
  int n = (blockIdx.x * 256 + threadIdx.x) >> 6;
  if (n >= N_NODES) return;
  int lane = threadIdx.x & 63;
  int beg = off[n], end = off[n + 1], deg = end - beg;
  float edn = ed[n];
  float ax = 0.f, ay = 0.f, az = 0.f, aw = 0.f;
  float invden;

  if (deg <= 64) {
    int sv = 0;
    float e = -1e30f;
    bool valid = lane < deg;
    if (valid) {
      sv = srcs[beg + lane];
      e = lrelu(es[sv] + edn);
    }
    float m = e;
#pragma unroll
    for (int s = 1; s < 64; s <<= 1) m = fmaxf(m, __shfl_xor(m, s));
    float wv = valid ? __expf(e - m) : 0.f;
    float den = wv;
#pragma unroll
    for (int s = 1; s < 64; s <<= 1) den += __shfl_xor(den, s);
    invden = 1.f / den;

    int j = 0;
    for (; j + 4 <= deg; j += 4) {
      int s0 = rli(sv, j), s1 = rli(sv, j + 1), s2 = rli(sv, j + 2), s3 = rli(sv, j + 3);
      ushort4 v0 = *reinterpret_cast<const ushort4*>(&h2[(size_t)s0 * 256 + lane * 4]);
      ushort4 v1 = *reinterpret_cast<const ushort4*>(&h2[(size_t)s1 * 256 + lane * 4]);
      ushort4 v2 = *reinterpret_cast<const ushort4*>(&h2[(size_t)s2 * 256 + lane * 4]);
      ushort4 v3 = *reinterpret_cast<const ushort4*>(&h2[(size_t)s3 * 256 + lane * 4]);
      float wj0 = rlf(wv, j), wj1 = rlf(wv, j + 1), wj2 = rlf(wv, j + 2), wj3 = rlf(wv, j + 3);
      ax = fmaf(wj0, bf2f(v0.x), ax); ay = fmaf(wj0, bf2f(v0.y), ay);
      az = fmaf(wj0, bf2f(v0.z), az); aw = fmaf(wj0, bf2f(v0.w), aw);
      ax = fmaf(wj1, bf2f(v1.x), ax); ay = fmaf(wj1, bf2f(v1.y), ay);
      az = fmaf(wj1, bf2f(v1.z), az); aw = fmaf(wj1, bf2f(v1.w), aw);
      ax = fmaf(wj2, bf2f(v2.x), ax); ay = fmaf(wj2, bf2f(v2.y), ay);
      az = fmaf(wj2, bf2f(v2.z), az); aw = fmaf(wj2, bf2f(v2.w), aw);
      ax = fmaf(wj3, bf2f(v3.x), ax); ay = fmaf(wj3, bf2f(v3.y), ay);
      az = fmaf(wj3, bf2f(v3.z), az); aw = fmaf(wj3, bf2f(v3.w), aw);
    }
    for (; j < deg; ++j) {
      int sj = rli(sv, j);
      float wj = rlf(wv, j);
      ushort4 v = *reinterpret_cast<const ushort4*>(&h2[(size_t)sj * 256 + lane * 4]);
      ax = fmaf(wj, bf2f(v.x), ax); ay = fmaf(wj, bf2f(v.y), ay);
      az = fmaf(wj, bf2f(v.z), az); aw = fmaf(wj, bf2f(v.w), aw);
    }
  } else {
    float m = -1e30f;
    for (int j = beg + lane; j < end; j += 64) m = fmaxf(m, lrelu(es[srcs[j]] + edn));
#pragma unroll
    for (int s = 1; s < 64; s <<= 1) m = fmaxf(m, __shfl_xor(m, s));
    float den = 0.f;
    for (int j = beg; j < end; ++j) {
      int s = srcs[j];
      float w = __expf(lrelu(es[s] + edn) - m);
      den += w;
      ushort4 v = *reinterpret_cast<const ushort4*>(&h2[(size_t)s * 256 + lane * 4]);
      ax = fmaf(w, bf2f(v.x), ax); ay = fmaf(w, bf2f(v.y), ay);
      az = fmaf(w, bf2f(v.z), az); aw = fmaf(w, bf2f(v.w), aw);
    }
    invden = 1.f / den;
  }

  float4 bb = *reinterpret_cast<const float4*>(&b2[lane * 4]);
  float4 o = make_float4(ax * invden + bb.x, ay * invden + bb.y, az * invden + bb.z, aw * invden + bb.w);
  *reinterpret_cast<float4*>(&out[(size_t)n * 256 + lane * 4]) = o;
}

extern "C" void kernel_launch(void* const* d_in, const int* in_sizes, int n_in,
                              void* d_out, int out_size, void* d_ws, size_t ws_size,
                              hipStream_t stream) {
  (void)in_sizes; (void)n_in; (void)out_size; (void)ws_size;
  const float* x   = (const float*)d_in[0];
  const int*   ei  = (const int*)d_in[1];
  const float* W1  = (const float*)d_in[2];
  const float* a1s = (const float*)d_in[3];
  const float* a1d = (const float*)d_in[4];
  const float* b1  = (const float*)d_in[5];
  const float* lng = (const float*)d_in[6];
  const float* lnb = (const float*)d_in[7];
  const float* W2  = (const float*)d_in[8];
  const float* a2s = (const float*)d_in[9];
  const float* a2d = (const float*)d_in[10];
  const float* b2  = (const float*)d_in[11];
  float* out = (float*)d_out;

  char* ws = (char*)d_ws;
  unsigned short* h1b  = (unsigned short*)(ws + 0);          // 10,240,000 B
  unsigned short* hmidb = (unsigned short*)(ws + 10240000);  // 10,240,000 B
  unsigned short* h2b  = (unsigned short*)(ws + 20480000);   // 10,240,000 B
  unsigned short* W1t  = (unsigned short*)(ws + 30720000);   // 131,072 B
  unsigned short* W2t  = (unsigned short*)(ws + 30851072);   // 131,072 B
  float* es1 = (float*)(ws + 30982144);                      // N*4 f32
  float* ed1 = (float*)(ws + 31302144);
  float* es2 = (float*)(ws + 31622144);                      // N f32
  float* ed2 = (float*)(ws + 31702144);
  int*   off = (int*)(ws + 31782144);                        // N+1
  int*   cnt = (int*)(ws + 31862148);                        // N
  int*   srcs = (int*)(ws + 31942148);                       // ETOT

  // CSR build
  hipMemsetAsync(cnt, 0, N_NODES * sizeof(int), stream);
  k_count<<<(N_ETOT + 255) / 256, 256, 0, stream>>>(ei, cnt);
  k_scan<<<1, 1024, 0, stream>>>(cnt, off);
  hipMemsetAsync(cnt, 0, N_NODES * sizeof(int), stream);
  k_scatter<<<(N_ETOT + 255) / 256, 256, 0, stream>>>(ei, off, cnt, srcs);

  // weight prep (bf16, transposed)
  k_prep<<<512, 256, 0, stream>>>(W1, W2, W1t, W2t);

  // layer 1
  k_mfma_gemm<0><<<625, 256, 0, stream>>>((const void*)x, W1t, h1b);
  k_dots<4><<<(N_NODES * 64) / 256, 256, 0, stream>>>(h1b, a1s, a1d, es1, ed1);
  k_gat1_ln<<<(N_NODES * 64) / 256, 256, 0, stream>>>(h1b, es1, ed1, off, srcs, b1, lng, lnb, hmidb);

  // layer 2
  k_mfma_gemm<1><<<625, 256, 0, stream>>>((const void*)hmidb, W2t, h2b);
  k_dots<1><<<(N_NODES * 64) / 256, 256, 0, stream>>>(h2b, a2s, a2d, es2, ed2);
  k_gat2<<<(N_NODES * 64) / 256, 256, 0, stream>>>(h2b, es2, ed2, off, srcs, b2, out);
}

// Round 4
// 232.777 us; speedup vs baseline: 1.5269x; 1.1748x over previous
//
#include <hip/hip_runtime.h>
#include <hip/hip_bf16.h>
#include <math.h>

#define N_NODES 20000
#define N_EDGES 320000
#define N_ETOT  (N_EDGES + N_NODES)
#define SLOPE 0.2f
#define LN_EPS 1e-5f

typedef __attribute__((ext_vector_type(8))) short short8v;
typedef __attribute__((ext_vector_type(4))) float f32x4;

__device__ __forceinline__ float lrelu(float x) { return x > 0.f ? x : SLOPE * x; }

__device__ __forceinline__ float rlf(float v, int l) {
  return __uint_as_float(__builtin_amdgcn_readlane(__float_as_uint(v), l));
}
__device__ __forceinline__ int rli(int v, int l) { return __builtin_amdgcn_readlane(v, l); }

__device__ __forceinline__ unsigned short f2bf(float f) {
  __hip_bfloat16 h = __float2bfloat16(f);
  return *reinterpret_cast<unsigned short*>(&h);
}
__device__ __forceinline__ float bf2f(unsigned short u) {
  return __uint_as_float(((unsigned int)u) << 16);
}

// ---------------- graph build: dst-grouped CSR ----------------
__global__ __launch_bounds__(256) void k_count(const int* __restrict__ ei, int* __restrict__ cnt) {
  int i = blockIdx.x * 256 + threadIdx.x;
  if (i >= N_ETOT) return;
  int d = (i < N_EDGES) ? ei[N_EDGES + i] : (i - N_EDGES);
  atomicAdd(&cnt[d], 1);
}

// scan also zeroes cnt (reused as scatter cursor)
__global__ __launch_bounds__(1024) void k_scan(int* __restrict__ cnt, int* __restrict__ off) {
  __shared__ int wsum[16], wpref[16];
  __shared__ int base_s;
  int tid = threadIdx.x, lane = tid & 63, wid = tid >> 6;
  if (tid == 0) { base_s = 0; off[0] = 0; }
  __syncthreads();
  for (int c = 0; c < 20; ++c) {
    int i = c * 1024 + tid;
    int v = (i < N_NODES) ? cnt[i] : 0;
    if (i < N_NODES) cnt[i] = 0;
    int incl = v;
#pragma unroll
    for (int d = 1; d < 64; d <<= 1) { int t = __shfl_up(incl, d); if (lane >= d) incl += t; }
    if (lane == 63) wsum[wid] = incl;
    __syncthreads();
    if (wid == 0 && lane < 16) {
      int s = wsum[lane];
#pragma unroll
      for (int d = 1; d < 16; d <<= 1) { int t = __shfl_up(s, d); if (lane >= d) s += t; }
      wpref[lane] = s;
    }
    __syncthreads();
    int wbase = wid ? wpref[wid - 1] : 0;
    if (i < N_NODES) off[i + 1] = base_s + wbase + incl;
    __syncthreads();
    if (tid == 0) base_s += wpref[15];
    __syncthreads();
  }
}

__global__ __launch_bounds__(256) void k_scatter(const int* __restrict__ ei, const int* __restrict__ off,
                                                 int* __restrict__ cursor, int* __restrict__ srcs) {
  int i = blockIdx.x * 256 + threadIdx.x;
  if (i >= N_ETOT) return;
  int s, d;
  if (i < N_EDGES) { s = ei[i]; d = ei[N_EDGES + i]; } else { s = i - N_EDGES; d = s; }
  int pos = off[d] + atomicAdd(&cursor[d], 1);
  srcs[pos] = s;
}

// ---------------- prep: W[256][256] (k-major) -> fragment-packed bf16 ----------------
// Wpack flat index: ((((nhalf*8 + ks)*8 + nf)*64 + lane)*8 + j)
// value = W[k][col], col = nhalf*128 + nf*16 + (lane&15), k = ks*32 + (lane>>4)*8 + j
__global__ __launch_bounds__(256) void k_prep(const float* __restrict__ W1, const float* __restrict__ W2,
                                              unsigned short* __restrict__ P1, unsigned short* __restrict__ P2) {
  int b = blockIdx.x, t = threadIdx.x;
  int e = (b & 255) * 256 + t;
  int j = e & 7, lane = (e >> 3) & 63, nf = (e >> 9) & 7, ks = (e >> 12) & 7, nh = (e >> 15) & 1;
  int col = nh * 128 + nf * 16 + (lane & 15);
  int k = ks * 32 + (lane >> 4) * 8 + j;
  if (b < 256) P1[e] = f2bf(W1[k * 256 + col]);
  else         P2[e] = f2bf(W2[k * 256 + col]);
}

// ---------------- MFMA GEMM + fused attention dots ----------------
// C_bf16[M,256] = A[M,256] @ W; per-wave 16x128 tile; es/ed accumulated via atomics.
template <int A_BF16, int HEADS>
__global__ __launch_bounds__(256) void k_mfma_gemm(const void* __restrict__ Av,
                                                   const unsigned short* __restrict__ Wp,
                                                   const float* __restrict__ asrc,
                                                   const float* __restrict__ adst,
                                                   unsigned short* __restrict__ C,
                                                   float* __restrict__ es, float* __restrict__ ed) {
  int gwave = blockIdx.x * 4 + (threadIdx.x >> 6);
  int wtile = gwave >> 1;
  int nhalf = gwave & 1;
  int lane = threadIdx.x & 63;
  int r = lane & 15, kg = lane >> 4;
  int rbase = wtile * 16;
  int cbase = nhalf * 128;

  f32x4 acc[8];
#pragma unroll
  for (int i = 0; i < 8; ++i) acc[i] = (f32x4){0.f, 0.f, 0.f, 0.f};

  const float* Af = (const float*)Av;
  const unsigned short* Ab = (const unsigned short*)Av;
  const unsigned short* Wb = Wp + nhalf * 32768;

#pragma unroll
  for (int ks = 0; ks < 8; ++ks) {
    int koff = ks * 32 + kg * 8;
    short8v a;
    if (A_BF16) {
      int4 raw = *reinterpret_cast<const int4*>(&Ab[(size_t)(rbase + r) * 256 + koff]);
      a = __builtin_bit_cast(short8v, raw);
    } else {
      float4 lo = *reinterpret_cast<const float4*>(&Af[(size_t)(rbase + r) * 256 + koff]);
      float4 hi = *reinterpret_cast<const float4*>(&Af[(size_t)(rbase + r) * 256 + koff + 4]);
      a[0] = (short)f2bf(lo.x); a[1] = (short)f2bf(lo.y); a[2] = (short)f2bf(lo.z); a[3] = (short)f2bf(lo.w);
      a[4] = (short)f2bf(hi.x); a[5] = (short)f2bf(hi.y); a[6] = (short)f2bf(hi.z); a[7] = (short)f2bf(hi.w);
    }
#pragma unroll
    for (int nf = 0; nf < 8; ++nf) {
      int4 braw = *reinterpret_cast<const int4*>(&Wb[(size_t)(ks * 8 + nf) * 512 + lane * 8]);
      short8v b = __builtin_bit_cast(short8v, braw);
      acc[nf] = __builtin_amdgcn_mfma_f32_16x16x32_bf16(a, b, acc[nf], 0, 0, 0);
    }
  }

  // store C (bf16)
#pragma unroll
  for (int nf = 0; nf < 8; ++nf) {
#pragma unroll
    for (int q = 0; q < 4; ++q) {
      int row = rbase + kg * 4 + q;
      int col = cbase + nf * 16 + r;
      C[(size_t)row * 256 + col] = f2bf(acc[nf][q]);
    }
  }

  // fused dots: per-row <h, a_src>, <h, a_dst> partials -> atomicAdd
  float as_v[8], ad_v[8];
#pragma unroll
  for (int nf = 0; nf < 8; ++nf) {
    int col = cbase + nf * 16 + r;
    as_v[nf] = asrc[col];
    ad_v[nf] = adst[col];
  }
  if (HEADS == 4) {
    // nf 0..3 -> head 2*nhalf, nf 4..7 -> head 2*nhalf+1
#pragma unroll
    for (int q = 0; q < 4; ++q) {
      float s0 = 0.f, s1 = 0.f, d0 = 0.f, d1 = 0.f;
#pragma unroll
      for (int nf = 0; nf < 4; ++nf) {
        s0 = fmaf(acc[nf][q], as_v[nf], s0);
        d0 = fmaf(acc[nf][q], ad_v[nf], d0);
        s1 = fmaf(acc[nf + 4][q], as_v[nf + 4], s1);
        d1 = fmaf(acc[nf + 4][q], ad_v[nf + 4], d1);
      }
#pragma unroll
      for (int s = 1; s < 16; s <<= 1) {
        s0 += __shfl_xor(s0, s); s1 += __shfl_xor(s1, s);
        d0 += __shfl_xor(d0, s); d1 += __shfl_xor(d1, s);
      }
      if (r == 0) {
        int row = rbase + kg * 4 + q;
        int hl = nhalf * 2;
        atomicAdd(&es[row * 4 + hl], s0);
        atomicAdd(&es[row * 4 + hl + 1], s1);
        atomicAdd(&ed[row * 4 + hl], d0);
        atomicAdd(&ed[row * 4 + hl + 1], d1);
      }
    }
  } else {
#pragma unroll
    for (int q = 0; q < 4; ++q) {
      float s0 = 0.f, d0 = 0.f;
#pragma unroll
      for (int nf = 0; nf < 8; ++nf) {
        s0 = fmaf(acc[nf][q], as_v[nf], s0);
        d0 = fmaf(acc[nf][q], ad_v[nf], d0);
      }
#pragma unroll
      for (int s = 1; s < 16; s <<= 1) {
        s0 += __shfl_xor(s0, s);
        d0 += __shfl_xor(d0, s);
      }
      if (r == 0) {
        int row = rbase + kg * 4 + q;
        atomicAdd(&es[row], s0);
        atomicAdd(&ed[row], d0);
      }
    }
  }
}

// ---------------- layer 1 aggregate (4 heads x 64ch, bf16 h) + bias + LN + ReLU -> bf16 ----------------
__global__ __launch_bounds__(256) void k_gat1_ln(const unsigned short* __restrict__ h1,
                                                 const float* __restrict__ es, const float* __restrict__ ed,
                                                 const int* __restrict__ off, const int* __restrict__ srcs,
                                                 const float* __restrict__ b1, const float* __restrict__ lng,
                                                 const float* __restrict__ lnb, unsigned short* __restrict__ hmid) {
  int n = (blockIdx.x * 256 + threadIdx.x) >> 6;
  if (n >= N_NODES) return;
  int lane = threadIdx.x & 63;
  int myh = lane >> 4;
  int beg = off[n], end = off[n + 1], deg = end - beg;
  float4 edv = *reinterpret_cast<const float4*>(&ed[n * 4]);
  float ax = 0.f, ay = 0.f, az = 0.f, aw = 0.f;
  float invden;

  if (deg <= 64) {
    int sv = 0;
    float e0 = -1e30f, e1 = -1e30f, e2 = -1e30f, e3 = -1e30f;
    bool valid = lane < deg;
    if (valid) {
      sv = srcs[beg + lane];
      float4 esv = *reinterpret_cast<const float4*>(&es[sv * 4]);
      e0 = lrelu(esv.x + edv.x); e1 = lrelu(esv.y + edv.y);
      e2 = lrelu(esv.z + edv.z); e3 = lrelu(esv.w + edv.w);
    }
    float m0 = e0, m1 = e1, m2 = e2, m3 = e3;
#pragma unroll
    for (int s = 1; s < 64; s <<= 1) {
      m0 = fmaxf(m0, __shfl_xor(m0, s)); m1 = fmaxf(m1, __shfl_xor(m1, s));
      m2 = fmaxf(m2, __shfl_xor(m2, s)); m3 = fmaxf(m3, __shfl_xor(m3, s));
    }
    float w0 = valid ? __expf(e0 - m0) : 0.f;
    float w1 = valid ? __expf(e1 - m1) : 0.f;
    float w2 = valid ? __expf(e2 - m2) : 0.f;
    float w3 = valid ? __expf(e3 - m3) : 0.f;
    float d0 = w0, d1 = w1, d2 = w2, d3 = w3;
#pragma unroll
    for (int s = 1; s < 64; s <<= 1) {
      d0 += __shfl_xor(d0, s); d1 += __shfl_xor(d1, s);
      d2 += __shfl_xor(d2, s); d3 += __shfl_xor(d3, s);
    }
    float den = (myh == 0) ? d0 : (myh == 1) ? d1 : (myh == 2) ? d2 : d3;
    invden = 1.f / den;

    int j = 0;
    for (; j + 4 <= deg; j += 4) {
      int s0 = rli(sv, j), s1 = rli(sv, j + 1), s2 = rli(sv, j + 2), s3 = rli(sv, j + 3);
      ushort4 v0 = *reinterpret_cast<const ushort4*>(&h1[(size_t)s0 * 256 + lane * 4]);
      ushort4 v1 = *reinterpret_cast<const ushort4*>(&h1[(size_t)s1 * 256 + lane * 4]);
      ushort4 v2 = *reinterpret_cast<const ushort4*>(&h1[(size_t)s2 * 256 + lane * 4]);
      ushort4 v3 = *reinterpret_cast<const ushort4*>(&h1[(size_t)s3 * 256 + lane * 4]);
#pragma unroll
      for (int q = 0; q < 4; ++q) {
        int jj = j + q;
        float w0j = rlf(w0, jj), w1j = rlf(w1, jj), w2j = rlf(w2, jj), w3j = rlf(w3, jj);
        float wj = (myh == 0) ? w0j : (myh == 1) ? w1j : (myh == 2) ? w2j : w3j;
        ushort4 v = (q == 0) ? v0 : (q == 1) ? v1 : (q == 2) ? v2 : v3;
        ax = fmaf(wj, bf2f(v.x), ax); ay = fmaf(wj, bf2f(v.y), ay);
        az = fmaf(wj, bf2f(v.z), az); aw = fmaf(wj, bf2f(v.w), aw);
      }
    }
    for (; j < deg; ++j) {
      int sj = rli(sv, j);
      float w0j = rlf(w0, j), w1j = rlf(w1, j), w2j = rlf(w2, j), w3j = rlf(w3, j);
      float wj = (myh == 0) ? w0j : (myh == 1) ? w1j : (myh == 2) ? w2j : w3j;
      ushort4 v = *reinterpret_cast<const ushort4*>(&h1[(size_t)sj * 256 + lane * 4]);
      ax = fmaf(wj, bf2f(v.x), ax); ay = fmaf(wj, bf2f(v.y), ay);
      az = fmaf(wj, bf2f(v.z), az); aw = fmaf(wj, bf2f(v.w), aw);
    }
  } else {
    float m0 = -1e30f, m1 = -1e30f, m2 = -1e30f, m3 = -1e30f;
    for (int j = beg + lane; j < end; j += 64) {
      int s = srcs[j];
      float4 esv = *reinterpret_cast<const float4*>(&es[s * 4]);
      m0 = fmaxf(m0, lrelu(esv.x + edv.x)); m1 = fmaxf(m1, lrelu(esv.y + edv.y));
      m2 = fmaxf(m2, lrelu(esv.z + edv.z)); m3 = fmaxf(m3, lrelu(esv.w + edv.w));
    }
#pragma unroll
    for (int s = 1; s < 64; s <<= 1) {
      m0 = fmaxf(m0, __shfl_xor(m0, s)); m1 = fmaxf(m1, __shfl_xor(m1, s));
      m2 = fmaxf(m2, __shfl_xor(m2, s)); m3 = fmaxf(m3, __shfl_xor(m3, s));
    }
    float edh = (myh == 0) ? edv.x : (myh == 1) ? edv.y : (myh == 2) ? edv.z : edv.w;
    float mh = (myh == 0) ? m0 : (myh == 1) ? m1 : (myh == 2) ? m2 : m3;
    float den = 0.f;
    for (int j = beg; j < end; ++j) {
      int s = srcs[j];
      float e = lrelu(es[s * 4 + myh] + edh);
      float w = __expf(e - mh);
      den += w;
      ushort4 v = *reinterpret_cast<const ushort4*>(&h1[(size_t)s * 256 + lane * 4]);
      ax = fmaf(w, bf2f(v.x), ax); ay = fmaf(w, bf2f(v.y), ay);
      az = fmaf(w, bf2f(v.z), az); aw = fmaf(w, bf2f(v.w), aw);
    }
    invden = 1.f / den;
  }

  float4 bb = *reinterpret_cast<const float4*>(&b1[lane * 4]);
  float vx = ax * invden + bb.x, vy = ay * invden + bb.y;
  float vz = az * invden + bb.z, vw = aw * invden + bb.w;
  float sum = vx + vy + vz + vw;
  float sq = vx * vx + vy * vy + vz * vz + vw * vw;
#pragma unroll
  for (int s = 1; s < 64; s <<= 1) { sum += __shfl_xor(sum, s); sq += __shfl_xor(sq, s); }
  float mu = sum * (1.f / 256.f);
  float var = sq * (1.f / 256.f) - mu * mu;
  float rstd = rsqrtf(var + LN_EPS);
  float4 g = *reinterpret_cast<const float4*>(&lng[lane * 4]);
  float4 lb = *reinterpret_cast<const float4*>(&lnb[lane * 4]);
  ushort4 o;
  o.x = f2bf(fmaxf(0.f, (vx - mu) * rstd * g.x + lb.x));
  o.y = f2bf(fmaxf(0.f, (vy - mu) * rstd * g.y + lb.y));
  o.z = f2bf(fmaxf(0.f, (vz - mu) * rstd * g.z + lb.z));
  o.w = f2bf(fmaxf(0.f, (vw - mu) * rstd * g.w + lb.w));
  *reinterpret_cast<ushort4*>(&hmid[(size_t)n * 256 + lane * 4]) = o;
}

// ---------------- layer 2 aggregate (1 head x 256ch, bf16 h) + bias -> out f32 ----------------
__global__ __launch_bounds__(256) void k_gat2(const unsigned short* __restrict__ h2,
                                              const float* __restrict__ es, const float* __restrict__ ed,
                                              const int* __restrict__ off, const int* __restrict__ srcs,
                                              const float* __restrict__ b2, float* __restrict__ out) {
  int n = (blockIdx.x * 256 + threadIdx.x) >> 6;
  if (n >= N_NODES) return;
  int lane = threadIdx.x & 63;
  int beg = off[n], end = off[n + 1], deg = end - beg;
  float edn = ed[n];
  float ax = 0.f, ay = 0.f, az = 0.f, aw = 0.f;
  float invden;

  if (deg <= 64) {
    int sv = 0;
    float e = -1e30f;
    bool valid = lane < deg;
    if (valid) {
      sv = srcs[beg + lane];
      e = lrelu(es[sv] + edn);
    }
    float m = e;
#pragma unroll
    for (int s = 1; s < 64; s <<= 1) m = fmaxf(m, __shfl_xor(m, s));
    float wv = valid ? __expf(e - m) : 0.f;
    float den = wv;
#pragma unroll
    for (int s = 1; s < 64; s <<= 1) den += __shfl_xor(den, s);
    invden = 1.f / den;

    int j = 0;
    for (; j + 4 <= deg; j += 4) {
      int s0 = rli(sv, j), s1 = rli(sv, j + 1), s2 = rli(sv, j + 2), s3 = rli(sv, j + 3);
      ushort4 v0 = *reinterpret_cast<const ushort4*>(&h2[(size_t)s0 * 256 + lane * 4]);
      ushort4 v1 = *reinterpret_cast<const ushort4*>(&h2[(size_t)s1 * 256 + lane * 4]);
      ushort4 v2 = *reinterpret_cast<const ushort4*>(&h2[(size_t)s2 * 256 + lane * 4]);
      ushort4 v3 = *reinterpret_cast<const ushort4*>(&h2[(size_t)s3 * 256 + lane * 4]);
      float wj0 = rlf(wv, j), wj1 = rlf(wv, j + 1), wj2 = rlf(wv, j + 2), wj3 = rlf(wv, j + 3);
      ax = fmaf(wj0, bf2f(v0.x), ax); ay = fmaf(wj0, bf2f(v0.y), ay);
      az = fmaf(wj0, bf2f(v0.z), az); aw = fmaf(wj0, bf2f(v0.w), aw);
      ax = fmaf(wj1, bf2f(v1.x), ax); ay = fmaf(wj1, bf2f(v1.y), ay);
      az = fmaf(wj1, bf2f(v1.z), az); aw = fmaf(wj1, bf2f(v1.w), aw);
      ax = fmaf(wj2, bf2f(v2.x), ax); ay = fmaf(wj2, bf2f(v2.y), ay);
      az = fmaf(wj2, bf2f(v2.z), az); aw = fmaf(wj2, bf2f(v2.w), aw);
      ax = fmaf(wj3, bf2f(v3.x), ax); ay = fmaf(wj3, bf2f(v3.y), ay);
      az = fmaf(wj3, bf2f(v3.z), az); aw = fmaf(wj3, bf2f(v3.w), aw);
    }
    for (; j < deg; ++j) {
      int sj = rli(sv, j);
      float wj = rlf(wv, j);
      ushort4 v = *reinterpret_cast<const ushort4*>(&h2[(size_t)sj * 256 + lane * 4]);
      ax = fmaf(wj, bf2f(v.x), ax); ay = fmaf(wj, bf2f(v.y), ay);
      az = fmaf(wj, bf2f(v.z), az); aw = fmaf(wj, bf2f(v.w), aw);
    }
  } else {
    float m = -1e30f;
    for (int j = beg + lane; j < end; j += 64) m = fmaxf(m, lrelu(es[srcs[j]] + edn));
#pragma unroll
    for (int s = 1; s < 64; s <<= 1) m = fmaxf(m, __shfl_xor(m, s));
    float den = 0.f;
    for (int j = beg; j < end; ++j) {
      int s = srcs[j];
      float w = __expf(lrelu(es[s] + edn) - m);
      den += w;
      ushort4 v = *reinterpret_cast<const ushort4*>(&h2[(size_t)s * 256 + lane * 4]);
      ax = fmaf(w, bf2f(v.x), ax); ay = fmaf(w, bf2f(v.y), ay);
      az = fmaf(w, bf2f(v.z), az); aw = fmaf(w, bf2f(v.w), aw);
    }
    invden = 1.f / den;
  }

  float4 bb = *reinterpret_cast<const float4*>(&b2[lane * 4]);
  float4 o = make_float4(ax * invden + bb.x, ay * invden + bb.y, az * invden + bb.z, aw * invden + bb.w);
  *reinterpret_cast<float4*>(&out[(size_t)n * 256 + lane * 4]) = o;
}

extern "C" void kernel_launch(void* const* d_in, const int* in_sizes, int n_in,
                              void* d_out, int out_size, void* d_ws, size_t ws_size,
                              hipStream_t stream) {
  (void)in_sizes; (void)n_in; (void)out_size; (void)ws_size;
  const float* x   = (const float*)d_in[0];
  const int*   ei  = (const int*)d_in[1];
  const float* W1  = (const float*)d_in[2];
  const float* a1s = (const float*)d_in[3];
  const float* a1d = (const float*)d_in[4];
  const float* b1  = (const float*)d_in[5];
  const float* lng = (const float*)d_in[6];
  const float* lnb = (const float*)d_in[7];
  const float* W2  = (const float*)d_in[8];
  const float* a2s = (const float*)d_in[9];
  const float* a2d = (const float*)d_in[10];
  const float* b2  = (const float*)d_in[11];
  float* out = (float*)d_out;

  char* ws = (char*)d_ws;
  unsigned short* h1b   = (unsigned short*)(ws + 0);
  unsigned short* hmidb = (unsigned short*)(ws + 10240000);
  unsigned short* h2b   = (unsigned short*)(ws + 20480000);
  unsigned short* Wp1   = (unsigned short*)(ws + 30720000);   // 131,072 B
  unsigned short* Wp2   = (unsigned short*)(ws + 30851072);   // 131,072 B
  float* es1 = (float*)(ws + 30982144);                       // 320,000 B
  float* ed1 = (float*)(ws + 31302144);                       // 320,000 B
  float* es2 = (float*)(ws + 31622144);                       // 80,000 B
  float* ed2 = (float*)(ws + 31702144);                       // 80,000 B  (es/ed contiguous: 800,000 B)
  int*   off = (int*)(ws + 31782144);                         // N+1
  int*   cnt = (int*)(ws + 31862148);                         // N
  int*   srcs = (int*)(ws + 31942148);                        // ETOT

  // zero: cnt + all es/ed (one memset each)
  hipMemsetAsync(cnt, 0, N_NODES * sizeof(int), stream);
  hipMemsetAsync(es1, 0, 800000, stream);

  // CSR build
  k_count<<<(N_ETOT + 255) / 256, 256, 0, stream>>>(ei, cnt);
  k_scan<<<1, 1024, 0, stream>>>(cnt, off);
  k_scatter<<<(N_ETOT + 255) / 256, 256, 0, stream>>>(ei, off, cnt, srcs);

  // weight prep (fragment-packed bf16)
  k_prep<<<512, 256, 0, stream>>>(W1, W2, Wp1, Wp2);

  // layer 1: GEMM + fused dots
  k_mfma_gemm<0, 4><<<625, 256, 0, stream>>>((const void*)x, Wp1, a1s, a1d, h1b, es1, ed1);
  k_gat1_ln<<<(N_NODES * 64) / 256, 256, 0, stream>>>(h1b, es1, ed1, off, srcs, b1, lng, lnb, hmidb);

  // layer 2: GEMM + fused dots
  k_mfma_gemm<1, 1><<<625, 256, 0, stream>>>((const void*)hmidb, Wp2, a2s, a2d, h2b, es2, ed2);
  k_gat2<<<(N_NODES * 64) / 256, 256, 0, stream>>>(h2b, es2, ed2, off, srcs, b2, out);
}